// Round 13
// baseline (35.095 us; speedup 1.0000x reference)
//
#include <hip/hip_runtime.h>
#include <math.h>

#define BB 32
#define II 512
#define OO 512
#define NN 16

#define NW 2            // n-window: the two nearest centers (lo = floor(nc))
#define LOMAX (NN - NW) // 14
#define OPB 8           // o's per block -> 512 B contiguous param segments
#define CHI 8           // i's per block
#define QS (II / CHI)   // 64 i-slices; ws = QS*OO*BB floats = 4 MB
#define NOB (OO / OPB)  // 64 o-blocks; grid = QS*NOB = 4096
#define XP (CHI + 1)    // xs pitch 9 (odd -> conflict-free)

#if __has_builtin(__builtin_amdgcn_exp2f)
#define EXP2F(x) __builtin_amdgcn_exp2f(x)
#else
#define EXP2F(x) exp2f(x)
#endif
#if __has_builtin(__builtin_amdgcn_rcpf)
#define RCPF(x) __builtin_amdgcn_rcpf(x)
#else
#define RCPF(x) (1.0f / (x))
#endif

// KS = sqrt(log2 e): zs = z*KS so exp(-z^2) = exp2(-zs^2)
// K_A2N = (1/sqrt(2))/KS: u = alpha*z/sqrt(2) = (alpha*K_A2N)*zs
#define KS      1.2011224087f
#define K_A2N   0.5887050112f
// A&S 7.1.27: erf(x) = 1 - (1 + a1 x + a2 x^2 + a3 x^3 + a4 x^4)^-4, |err|<=5e-4
#define EA1 0.278393f
#define EA2 0.230389f
#define EA3 0.000972f
#define EA4 0.078108f

// R12 + granularity lever pushed to 512 B (OPB=8), geometry held constant:
// CHI 32->8, QS 16->64 keeps grid=4096, per-thread work=16 elems, LDS~26 KB
// (6 blocks/CU). Param staging: per i-row, 32 threads x float4 = 512 B
// contiguous ascending (sigma/alpha/w each). ws layout switched to
// [q][o][b]: block stores 8 o-rows x 128 B contiguous (R12's [q][b][o]
// wrote 8 B combs -> 4-8x write amplification). Body math unchanged
// (proven, absmax 2.44e-4).
__global__ __launch_bounds__(256, 6)
void kat_win(const float* __restrict__ x,
             const float* __restrict__ mx_train,
             const float* __restrict__ scale,
             const float* __restrict__ sigma,
             const float* __restrict__ alpha,
             const float* __restrict__ w,
             const float* __restrict__ mx_start,
             float* __restrict__ ws)
{
    __shared__ float4 pr[CHI * OPB * NN];  // 16 KB [ii][op][n] {c1s,c0s,a2n,w}
    __shared__ float  xs[BB * XP];         // 1.15 KB [b][ii]
    __shared__ float2 sc[CHI * OPB];       // 512 B [ii][op]
    __shared__ float  red[OPB][8][BB];     // 8 KB

    const int bid = blockIdx.x;
    const int ob  = bid & (NOB - 1);
    const int q   = bid >> 6;            // NOB = 64
    const int o0  = ob * OPB;
    const int i0  = q * CHI;
    const int tid = threadIdx.x;
    const int b   = tid & 31;
    const int iw  = tid >> 5;            // 0..7 == this thread's i

    // ---- stage x[b][i0+ii] -> xs (256 elems, one shot) ----
    {
        const int bb = tid >> 3;         // 0..31
        const int ii = tid & 7;
        xs[bb * XP + ii] = x[bb * II + i0 + ii];
    }
    // ---- stage per-tuple constants: 4 pr entries per thread,
    //      512 B contiguous per i-row, ascending with tid ----
    {
        const int il = tid >> 5;             // 0..7
        const int op = (tid >> 2) & 7;       // 0..7
        const int n0 = (tid & 3) * 4;        // 0,4,8,12
        const int io = (i0 + il) * OO + o0 + op;
        const float4 sg4 = *reinterpret_cast<const float4*>(&sigma[io * NN + n0]);
        const float4 al4 = *reinterpret_cast<const float4*>(&alpha[io * NN + n0]);
        const float4 w4  = *reinterpret_cast<const float4*>(&w[io * NN + n0]);
        const float4 mx4 = *reinterpret_cast<const float4*>(&mx_start[n0]);
        const float  sca = fabsf(scale[io]);
        const float  mxt = mx_train[io];

        const float sg[4] = {sg4.x, sg4.y, sg4.z, sg4.w};
        const float al[4] = {al4.x, al4.y, al4.z, al4.w};
        const float wv[4] = {w4.x,  w4.y,  w4.z,  w4.w};
        const float mx[4] = {mx4.x, mx4.y, mx4.z, mx4.w};
        float4* dst = &pr[(il * OPB + op) * NN + n0];
#pragma unroll
        for (int c = 0; c < 4; ++c) {
            const float c1s = KS * RCPF(fabsf(sg[c]) + 1e-8f);
            const float ctr = fmaf(sca, mx[c], mxt);
            dst[c] = make_float4(c1s, -ctr * c1s, al[c] * K_A2N, wv[c]);
        }
    }
    // ---- stage window coefs: nc = (x - mxt)*15/|s| ----
    if (tid < CHI * OPB) {               // 64
        const int ii = tid >> 3;
        const int op = tid & 7;
        const int io = (i0 + ii) * OO + o0 + op;
        const float s   = fmaxf(fabsf(scale[io]), 1e-20f);
        const float inv = 15.0f * RCPF(s);
        sc[ii * OPB + op] = make_float2(inv, -mx_train[io] * inv);
    }
    __syncthreads();

    // ---- compute: 1 i x 8 o per thread, NW=2 window each ----
    float acc[OPB];
#pragma unroll
    for (int op = 0; op < OPB; ++op) acc[op] = 0.0f;

    const float xv = xs[b * XP + iw];    // conflict-free (pitch 9)
#pragma unroll
    for (int op = 0; op < OPB; ++op) {
        const float2 s2 = sc[iw * OPB + op];
        const float  nc = fmaf(xv, s2.x, s2.y);
        const float lof = fminf(fmaxf(floorf(nc), 0.0f), (float)LOMAX);
        const int   lo  = (int)lof;
        const float4* pp = &pr[(iw * OPB + op) * NN + lo];
#pragma unroll
        for (int k = 0; k < NW; ++k) {
            const float4 P = pp[k];
            const float zs = fmaf(xv, P.x, P.y);     // z*sqrt(log2e)
            const float m  = -zs * zs;
            const float e  = EXP2F(m);               // exp(-z^2)
            const float u  = P.z * zs;               // alpha*z/sqrt(2)
            const float au = fabsf(u);
            float d = fmaf(EA4, au, EA3);
            d = fmaf(d, au, EA2);
            d = fmaf(d, au, EA1);
            d = fmaf(d, au, 1.0f);
            const float r  = RCPF(d);
            const float r2 = r * r;
            const float r4 = r2 * r2;
            const float erfu = __builtin_copysignf(1.0f - r4, u);
            const float gg   = fmaf(e, erfu, e);     // e*(1+erf(u))
            acc[op] = fmaf(gg, P.w, acc[op]);
        }
    }

    // ---- reduce over iw; store ws[q][o][b] (128 B coalesced rows) ----
#pragma unroll
    for (int op = 0; op < OPB; ++op) red[op][iw][b] = acc[op];
    __syncthreads();
    {
        const int op = tid >> 5;
        const int bb = tid & 31;
        float s = 0.0f;
#pragma unroll
        for (int k = 0; k < 8; ++k) s += red[op][k][bb];
        ws[q * (OO * BB) + (o0 + op) * BB + bb] = s;
    }
}

// out[b,o] = sum_q ws[q][o][b]; reads coalesced, tiny scattered out write.
__global__ __launch_bounds__(256)
void kat_reduce(const float* __restrict__ ws, float* __restrict__ out)
{
    const int tid = threadIdx.x;
    const int o   = blockIdx.x * 8 + (tid >> 5);
    const int bb  = tid & 31;
    float s = 0.0f;
#pragma unroll
    for (int qq = 0; qq < QS; ++qq) s += ws[qq * (OO * BB) + o * BB + bb];
    out[bb * OO + o] = s;
}

extern "C" void kernel_launch(void* const* d_in, const int* in_sizes, int n_in,
                              void* d_out, int out_size, void* d_ws, size_t ws_size,
                              hipStream_t stream)
{
    const float* x        = (const float*)d_in[0];
    const float* mx_train = (const float*)d_in[1];
    const float* scale    = (const float*)d_in[2];
    const float* sigma    = (const float*)d_in[3];
    const float* alpha    = (const float*)d_in[4];
    const float* w        = (const float*)d_in[5];
    const float* mx_start = (const float*)d_in[6];
    float* ws             = (float*)d_ws;      // QS * O * B floats = 4 MB
    float* out            = (float*)d_out;

    kat_win<<<QS * NOB, 256, 0, stream>>>(x, mx_train, scale, sigma,
                                          alpha, w, mx_start, ws);
    kat_reduce<<<OO / 8, 256, 0, stream>>>(ws, out);
}

// Round 14
// 21.718 us; speedup vs baseline: 1.6160x; 1.6160x over previous
//
#include <hip/hip_runtime.h>
#include <math.h>

#define BB 32
#define II 512
#define OO 512
#define NN 16

#define NW 2            // n-window: the two nearest centers (lo = floor(nc))
#define LOMAX (NN - NW) // 14
#define QS 16           // i-split (partials in ws); ws = QS*O*B floats = 1 MB
#define CHI 32          // i's per block
#define OPB 2           // o's per block -> 128 B contiguous param segments
#define NOB (OO / OPB)  // 256 o-blocks; grid = QS*NOB = 4096

#if __has_builtin(__builtin_amdgcn_exp2f)
#define EXP2F(x) __builtin_amdgcn_exp2f(x)
#else
#define EXP2F(x) exp2f(x)
#endif
#if __has_builtin(__builtin_amdgcn_rcpf)
#define RCPF(x) __builtin_amdgcn_rcpf(x)
#else
#define RCPF(x) (1.0f / (x))
#endif

// KS = sqrt(log2 e): zs = z*KS so exp(-z^2) = exp2(-zs^2)
// K_A2N = (1/sqrt(2))/KS: u = alpha*z/sqrt(2) = (alpha*K_A2N)*zs
#define KS      1.2011224087f
#define K_A2N   0.5887050112f
// A&S 7.1.27: erf(x) = 1 - (1 + a1 x + a2 x^2 + a3 x^3 + a4 x^4)^-4, |err|<=5e-4
#define EA1 0.278393f
#define EA2 0.230389f
#define EA3 0.000972f
#define EA4 0.078108f

// R12 (22.2 us anchor) + ONE change: ws layout [q][b][o] -> [q][o][b].
// R12's partial store wrote 32 rows x 8 B segments (2 floats, stride OO)
// -> ~8x HBM write amplification on 1 MB. Now each block writes 2 o-rows
// x 128 B contiguous; reduce reads [q][o][b] coalesced (256 B/wave/q) and
// eats a trivial 8 KB scattered final out write.
// (R13's OPB=8/CHI=8/QS=64 bundle regressed to 35 us — reverted.)
__global__ __launch_bounds__(256, 8)
void kat_win(const float* __restrict__ x,
             const float* __restrict__ mx_train,
             const float* __restrict__ scale,
             const float* __restrict__ sigma,
             const float* __restrict__ alpha,
             const float* __restrict__ w,
             const float* __restrict__ mx_start,
             float* __restrict__ ws)
{
    __shared__ float4 pr[CHI * OPB * NN];  // 16 KB [i][op][n] {c1s,c0s,a2n,w}
    __shared__ float  xs[BB * 33];         // 4.2 KB [b][ii], pitch 33
    __shared__ float2 sc[CHI * OPB];       // 512 B (inv_s15, -mxt*inv_s15)
    __shared__ float  red[OPB][8][BB];     // 2 KB

    const int bid = blockIdx.x;
    const int ob  = bid & (NOB - 1);
    const int q   = bid >> 8;
    const int o0  = ob * OPB;
    const int tid = threadIdx.x;
    const int b   = tid & 31;
    const int iw  = tid >> 5;
    const int i0  = q * CHI;

    // ---- stage x[b][i0+ii] -> xs (coalesced) ----
#pragma unroll
    for (int p = 0; p < (BB * CHI) / 256; ++p) {
        const int idx = p * 256 + tid;
        const int bb  = idx >> 5;
        const int ii  = idx & 31;
        xs[bb * 33 + ii] = x[bb * II + i0 + ii];
    }
    // ---- stage per-tuple constants: float4 per thread, 128 B/segment ----
    {
        const int il = tid >> 3;             // 0..31
        const int r  = tid & 7;              // 0..7 -> 8 float4 = 128 B per il
        const int op = r >> 2;               // 0..1
        const int n0 = (r & 3) * 4;          // 0,4,8,12
        const int io = (i0 + il) * OO + o0 + op;
        const float4 sg4 = *reinterpret_cast<const float4*>(&sigma[io * NN + n0]);
        const float4 al4 = *reinterpret_cast<const float4*>(&alpha[io * NN + n0]);
        const float4 w4  = *reinterpret_cast<const float4*>(&w[io * NN + n0]);
        const float4 mx4 = *reinterpret_cast<const float4*>(&mx_start[n0]);
        const float  sca = fabsf(scale[io]);
        const float  mxt = mx_train[io];

        const float sg[4] = {sg4.x, sg4.y, sg4.z, sg4.w};
        const float al[4] = {al4.x, al4.y, al4.z, al4.w};
        const float wv[4] = {w4.x,  w4.y,  w4.z,  w4.w};
        const float mx[4] = {mx4.x, mx4.y, mx4.z, mx4.w};
        float4* dst = &pr[(il * OPB + op) * NN + n0];
#pragma unroll
        for (int c = 0; c < 4; ++c) {
            const float c1s = KS * RCPF(fabsf(sg[c]) + 1e-8f);
            const float ctr = fmaf(sca, mx[c], mxt);
            dst[c] = make_float4(c1s, -ctr * c1s, al[c] * K_A2N, wv[c]);
        }
    }
    // ---- stage window coefs: nc = (x - mxt)*15/|s| ----
    if (tid < CHI * OPB) {
        const int ii  = tid >> 1;
        const int op  = tid & 1;
        const int io  = (i0 + ii) * OO + o0 + op;
        const float s   = fmaxf(fabsf(scale[io]), 1e-20f);
        const float inv = 15.0f * RCPF(s);
        sc[tid] = make_float2(inv, -mx_train[io] * inv);
    }
    __syncthreads();

    // ---- compute: 4 i x 2 o per thread, NW=2 window each ----
    float acc0 = 0.0f, acc1 = 0.0f;
#pragma unroll
    for (int j = 0; j < CHI / 8; ++j) {
        const int ii = iw + 8 * j;
        const float xv = xs[b * 33 + ii];
#pragma unroll
        for (int op = 0; op < OPB; ++op) {
            const float2 s2 = sc[ii * OPB + op];
            const float  nc = fmaf(xv, s2.x, s2.y);
            const float lof = fminf(fmaxf(floorf(nc), 0.0f), (float)LOMAX);
            const int   lo  = (int)lof;
            const float4* pp = &pr[(ii * OPB + op) * NN + lo];
            float a = 0.0f;
#pragma unroll
            for (int k = 0; k < NW; ++k) {
                const float4 P = pp[k];
                const float zs = fmaf(xv, P.x, P.y);     // z*sqrt(log2e)
                const float m  = -zs * zs;
                const float e  = EXP2F(m);               // exp(-z^2)
                const float u  = P.z * zs;               // alpha*z/sqrt(2)
                const float au = fabsf(u);
                float d = fmaf(EA4, au, EA3);
                d = fmaf(d, au, EA2);
                d = fmaf(d, au, EA1);
                d = fmaf(d, au, 1.0f);
                const float r  = RCPF(d);
                const float r2 = r * r;
                const float r4 = r2 * r2;
                const float erfu = __builtin_copysignf(1.0f - r4, u);
                const float gg   = fmaf(e, erfu, e);     // e*(1+erf(u))
                a = fmaf(gg, P.w, a);
            }
            if (op == 0) acc0 += a; else acc1 += a;
        }
    }

    // ---- reduce over iw; store ws[q][o][b]: 2 x 128 B contiguous rows ----
    red[0][iw][b] = acc0;
    red[1][iw][b] = acc1;
    __syncthreads();
    if (tid < OPB * BB) {
        const int op = tid >> 5;
        const int bb = tid & 31;
        float s = 0.0f;
#pragma unroll
        for (int k = 0; k < 8; ++k) s += red[op][k][bb];
        ws[q * (OO * BB) + (o0 + op) * BB + bb] = s;
    }
}

// out[b,o] = sum_q ws[q][o][b]; reads coalesced (256 B/wave/q),
// tiny (8 KB) scattered out write.
__global__ __launch_bounds__(256)
void kat_reduce(const float* __restrict__ ws, float* __restrict__ out)
{
    const int tid = threadIdx.x;
    const int o   = blockIdx.x * 8 + (tid >> 5);
    const int bb  = tid & 31;
    float s = 0.0f;
#pragma unroll
    for (int qq = 0; qq < QS; ++qq) s += ws[qq * (OO * BB) + o * BB + bb];
    out[bb * OO + o] = s;
}

extern "C" void kernel_launch(void* const* d_in, const int* in_sizes, int n_in,
                              void* d_out, int out_size, void* d_ws, size_t ws_size,
                              hipStream_t stream)
{
    const float* x        = (const float*)d_in[0];
    const float* mx_train = (const float*)d_in[1];
    const float* scale    = (const float*)d_in[2];
    const float* sigma    = (const float*)d_in[3];
    const float* alpha    = (const float*)d_in[4];
    const float* w        = (const float*)d_in[5];
    const float* mx_start = (const float*)d_in[6];
    float* ws             = (float*)d_ws;      // QS * O * B floats = 1 MB
    float* out            = (float*)d_out;

    kat_win<<<QS * NOB, 256, 0, stream>>>(x, mx_train, scale, sigma,
                                          alpha, w, mx_start, ws);
    kat_reduce<<<OO / 8, 256, 0, stream>>>(ws, out);
}